// Round 1
// baseline (623.982 us; speedup 1.0000x reference)
//
#include <hip/hip_runtime.h>
#include <hip/hip_bf16.h>

#define D_IN   256
#define HID    256
#define NNODES 100000
#define NEDGE  262144

// ---------------- Phase 1: C = X @ W  (M x 256) * (256 x 256) ----------------
// 128x128 tile, 256 threads, 8x8 micro-tile, K-step 16. fp32 VALU.
constexpr int TM = 128, TN = 128, TK = 16;

__global__ __launch_bounds__(256) void gemm_xw(
    const float* __restrict__ Xsrc, const float* __restrict__ Xdst,
    const float* __restrict__ W1, float* __restrict__ U, float* __restrict__ V)
{
    const int zz = blockIdx.z;                 // 0: U = Xsrc@W1[0:256], 1: V = Xdst@W1[256:512]
    const float* X = zz ? Xdst : Xsrc;
    const float* W = W1 + (size_t)zz * 256 * HID;
    float* C = zz ? V : U;

    const int m0 = blockIdx.x * TM;
    const int n0 = blockIdx.y * TN;

    __shared__ float As[TK][TM + 4];           // [k][m], stride 132 floats (528 B, 16B-mult)
    __shared__ float Bs[TK][TN];               // [k][n]

    const int tid = threadIdx.x;
    const int tx = tid & 15;                   // col group -> cols tx*8..tx*8+7
    const int ty = tid >> 4;                   // row group -> rows ty*8..ty*8+7

    float acc[8][8];
#pragma unroll
    for (int i = 0; i < 8; i++)
#pragma unroll
        for (int j = 0; j < 8; j++) acc[i][j] = 0.f;

    for (int ks = 0; ks < D_IN; ks += TK) {
        // A tile: 128 rows x 16 k = 512 float4 slots, transposed into As[k][m]
#pragma unroll
        for (int i = 0; i < 2; i++) {
            int s   = tid + i * 256;           // 0..511
            int row = s >> 2;
            int kk4 = (s & 3) << 2;
            int grow = m0 + row; if (grow >= NNODES) grow = NNODES - 1;
            const float4 a = *(const float4*)(X + (size_t)grow * D_IN + ks + kk4);
            As[kk4 + 0][row] = a.x;
            As[kk4 + 1][row] = a.y;
            As[kk4 + 2][row] = a.z;
            As[kk4 + 3][row] = a.w;
        }
        // B tile: 16 k x 128 n, contiguous
#pragma unroll
        for (int i = 0; i < 2; i++) {
            int s  = tid + i * 256;
            int kk = s >> 5;                   // 0..15
            int n4 = (s & 31) << 2;            // 0..124
            *(float4*)&Bs[kk][n4] = *(const float4*)(W + (size_t)(ks + kk) * HID + n0 + n4);
        }
        __syncthreads();
#pragma unroll
        for (int kk = 0; kk < TK; kk++) {
            float a[8], b[8];
            *(float4*)&a[0] = *(const float4*)&As[kk][ty * 8];
            *(float4*)&a[4] = *(const float4*)&As[kk][ty * 8 + 4];
            *(float4*)&b[0] = *(const float4*)&Bs[kk][tx * 8];
            *(float4*)&b[4] = *(const float4*)&Bs[kk][tx * 8 + 4];
#pragma unroll
            for (int i = 0; i < 8; i++)
#pragma unroll
                for (int j = 0; j < 8; j++)
                    acc[i][j] += a[i] * b[j];
        }
        __syncthreads();
    }
    // store 8x8 per thread
#pragma unroll
    for (int i = 0; i < 8; i++) {
        int grow = m0 + ty * 8 + i;
        if (grow < NNODES) {
            float4 c0 = {acc[i][0], acc[i][1], acc[i][2], acc[i][3]};
            float4 c1 = {acc[i][4], acc[i][5], acc[i][6], acc[i][7]};
            *(float4*)(C + (size_t)grow * HID + n0 + tx * 8)     = c0;
            *(float4*)(C + (size_t)grow * HID + n0 + tx * 8 + 4) = c1;
        }
    }
}

// ---------------- Phase 2: per-edge score, 1 wave per edge ----------------
__global__ __launch_bounds__(256) void edge_score(
    const float* __restrict__ U, const float* __restrict__ V,
    const float* __restrict__ b1, const float* __restrict__ W2,
    const float* __restrict__ b2,
    const int* __restrict__ epos, const int* __restrict__ eneg,
    float* __restrict__ out)
{
    const int wave = threadIdx.x >> 6;            // 0..3
    const int lane = threadIdx.x & 63;
    const int e = blockIdx.x * 4 + wave;          // 0 .. 2*NEDGE-1 exactly

    const int* ei = (e < NEDGE) ? epos : eneg;
    const int e2  = (e < NEDGE) ? e : e - NEDGE;
    const int s = ei[e2];
    const int d = ei[NEDGE + e2];

    const float4 u  = *(const float4*)(U  + (size_t)s * HID + lane * 4);
    const float4 v  = *(const float4*)(V  + (size_t)d * HID + lane * 4);
    const float4 bb = *(const float4*)(b1 + lane * 4);
    const float4 w  = *(const float4*)(W2 + lane * 4);

    float4 h;
    h.x = fmaxf(u.x + v.x + bb.x, 0.f);
    h.y = fmaxf(u.y + v.y + bb.y, 0.f);
    h.z = fmaxf(u.z + v.z + bb.z, 0.f);
    h.w = fmaxf(u.w + v.w + bb.w, 0.f);

    float p = h.x * w.x + h.y * w.y + h.z * w.z + h.w * w.w;
#pragma unroll
    for (int off = 32; off; off >>= 1)
        p += __shfl_down(p, off, 64);

    if (lane == 0) out[e] = p + b2[0];
}

// ---------------- Fallback (ws too small): direct per-edge MLP ----------------
__global__ __launch_bounds__(256) void edge_score_direct(
    const float* __restrict__ xs_, const float* __restrict__ xd_,
    const float* __restrict__ W1, const float* __restrict__ b1,
    const float* __restrict__ W2, const float* __restrict__ b2,
    const int* __restrict__ epos, const int* __restrict__ eneg,
    float* __restrict__ out)
{
    __shared__ float xrow[2 * D_IN];
    __shared__ float red[256];
    const int e = blockIdx.x;
    const int* ei = (e < NEDGE) ? epos : eneg;
    const int e2  = (e < NEDGE) ? e : e - NEDGE;
    const int s = ei[e2];
    const int d = ei[NEDGE + e2];
    const int t = threadIdx.x;

    xrow[t]         = xs_[(size_t)s * D_IN + t];
    xrow[D_IN + t]  = xd_[(size_t)d * D_IN + t];
    __syncthreads();

    float acc = b1[t];
    for (int k = 0; k < 2 * D_IN; k++)
        acc += xrow[k] * W1[(size_t)k * HID + t];
    acc = fmaxf(acc, 0.f);
    red[t] = acc * W2[t];
    __syncthreads();
    for (int st = 128; st; st >>= 1) {
        if (t < st) red[t] += red[t + st];
        __syncthreads();
    }
    if (t == 0) out[e] = red[0] + b2[0];
}

extern "C" void kernel_launch(void* const* d_in, const int* in_sizes, int n_in,
                              void* d_out, int out_size, void* d_ws, size_t ws_size,
                              hipStream_t stream) {
    const float* x_src = (const float*)d_in[0];
    const float* x_dst = (const float*)d_in[1];
    const float* W1    = (const float*)d_in[2];
    const float* b1    = (const float*)d_in[3];
    const float* W2    = (const float*)d_in[4];
    const float* b2    = (const float*)d_in[5];
    const int*   epos  = (const int*)d_in[6];
    const int*   eneg  = (const int*)d_in[7];
    float* out = (float*)d_out;

    const size_t need = 2ull * NNODES * HID * sizeof(float);
    if (ws_size >= need) {
        float* U = (float*)d_ws;
        float* V = U + (size_t)NNODES * HID;
        dim3 g1((NNODES + TM - 1) / TM, HID / TN, 2);
        gemm_xw<<<g1, 256, 0, stream>>>(x_src, x_dst, W1, U, V);
        edge_score<<<(2 * NEDGE) / 4, 256, 0, stream>>>(U, V, b1, W2, b2, epos, eneg, out);
    } else {
        edge_score_direct<<<2 * NEDGE, 256, 0, stream>>>(x_src, x_dst, W1, b1, W2, b2, epos, eneg, out);
    }
}

// Round 2
// 337.846 us; speedup vs baseline: 1.8469x; 1.8469x over previous
//
#include <hip/hip_runtime.h>

#define D_IN   256
#define HID    256
#define NNODES 100000
#define NEDGE  262144

typedef short short8   __attribute__((ext_vector_type(8)));
typedef float float4v  __attribute__((ext_vector_type(4)));

__device__ __forceinline__ unsigned short f32_to_bf16_rne(float f) {
    unsigned int u = __float_as_uint(f);
    unsigned int r = u + 0x7FFFu + ((u >> 16) & 1u);
    return (unsigned short)(r >> 16);
}
__device__ __forceinline__ float bf16_to_f32(unsigned short h) {
    return __uint_as_float(((unsigned int)h) << 16);
}

// -------- W1 (fp32 [2*256][256], k-major) -> Wt (bf16 [z][n][k], k-contiguous) --------
__global__ __launch_bounds__(256) void convert_w(
    const float* __restrict__ W1, unsigned short* __restrict__ Wt)
{
    const int b = blockIdx.x;          // 0..511
    const int z = b >> 8, n = b & 255;
    const int k = threadIdx.x;
    const float v = W1[((size_t)(z * 256 + k)) * HID + n];
    Wt[((size_t)(z * 256 + n)) * 256 + k] = f32_to_bf16_rne(v);
}

// -------- Phase 1: U = Xsrc@W1_top + b1 (bf16), V = Xdst@W1_bot (bf16) --------
// 128(M) x 256(N=full) tile, 512 threads = 8 waves (2x4), 64x64 per wave,
// BK=64, 16x16x32 bf16 MFMA, fp32->bf16 fused into LDS staging.
#define SA 72      // padded k-stride (ushorts): 144 B = 16B-mult, <=2-way bank alias

__global__ __launch_bounds__(512) void gemm_xw_mfma(
    const float* __restrict__ Xsrc, const float* __restrict__ Xdst,
    const unsigned short* __restrict__ Wt, const float* __restrict__ b1,
    unsigned short* __restrict__ U, unsigned short* __restrict__ V)
{
    const int zz = blockIdx.z;
    const float* X = zz ? Xdst : Xsrc;
    const unsigned short* Wz = Wt + (size_t)zz * 256 * 256;
    unsigned short* C = zz ? V : U;

    const int m0 = blockIdx.x * 128;

    __shared__ __align__(16) unsigned short smem[27648];   // 55.3 KB
    unsigned short* As = smem;          // [128][SA]
    unsigned short* Bs = smem + 9216;   // [256][SA]

    const int t = threadIdx.x;
    const int w = t >> 6, lane = t & 63;
    const int wm = w >> 2, wn = w & 3;          // 2 x 4 wave grid
    const int quad = lane >> 4, l16 = lane & 15;

    float4v acc[4][4];
#pragma unroll
    for (int mi = 0; mi < 4; mi++)
#pragma unroll
        for (int ni = 0; ni < 4; ni++) acc[mi][ni] = (float4v){0.f, 0.f, 0.f, 0.f};

    for (int ks = 0; ks < D_IN; ks += 64) {
        // A tile: 128 rows x 64 k fp32 -> bf16.  2048 float4 chunks / 512 thr = 4 each.
#pragma unroll
        for (int i = 0; i < 4; i++) {
            int s = t + i * 512;
            int row = s >> 4, c4 = (s & 15) << 2;
            int gr = m0 + row; if (gr >= NNODES) gr = NNODES - 1;
            float4 a = *(const float4*)(X + (size_t)gr * D_IN + ks + c4);
            ushort4 p;
            p.x = f32_to_bf16_rne(a.x); p.y = f32_to_bf16_rne(a.y);
            p.z = f32_to_bf16_rne(a.z); p.w = f32_to_bf16_rne(a.w);
            *(ushort4*)(As + row * SA + c4) = p;
        }
        // B tile: 256 n x 64 k bf16 from Wt (already [n][k]).  2048 x 16B / 512 = 4 each.
#pragma unroll
        for (int i = 0; i < 4; i++) {
            int s = t + i * 512;
            int n = s >> 3, seg = s & 7;
            *(int4*)(Bs + n * SA + seg * 8) =
                *(const int4*)(Wz + (size_t)n * 256 + ks + seg * 8);
        }
        __syncthreads();
#pragma unroll
        for (int kk = 0; kk < 64; kk += 32) {
            short8 af[4], bf[4];
#pragma unroll
            for (int mi = 0; mi < 4; mi++)
                af[mi] = *(const short8*)(As + (wm * 64 + mi * 16 + l16) * SA + kk + quad * 8);
#pragma unroll
            for (int ni = 0; ni < 4; ni++)
                bf[ni] = *(const short8*)(Bs + (wn * 64 + ni * 16 + l16) * SA + kk + quad * 8);
#pragma unroll
            for (int mi = 0; mi < 4; mi++)
#pragma unroll
                for (int ni = 0; ni < 4; ni++)
                    acc[mi][ni] = __builtin_amdgcn_mfma_f32_16x16x32_bf16(
                        af[mi], bf[ni], acc[mi][ni], 0, 0, 0);
        }
        __syncthreads();
    }

    // Epilogue: bias fold (z==0 adds b1), bf16 pack, LDS-staged coalesced store.
    float bias[4];
#pragma unroll
    for (int ni = 0; ni < 4; ni++)
        bias[ni] = (zz == 0) ? b1[wn * 64 + ni * 16 + l16] : 0.f;

    unsigned short* Cs = smem;          // [128][136] = 34.8 KB, aliases staging
#pragma unroll
    for (int h = 0; h < 2; h++) {       // n-halves 0..127, 128..255
        if ((wn >> 1) == h) {
#pragma unroll
            for (int mi = 0; mi < 4; mi++)
#pragma unroll
                for (int ni = 0; ni < 4; ni++) {
                    int cl = (wn & 1) * 64 + ni * 16 + l16;
#pragma unroll
                    for (int r = 0; r < 4; r++) {
                        int row = wm * 64 + mi * 16 + quad * 4 + r;
                        Cs[row * 136 + cl] = f32_to_bf16_rne(acc[mi][ni][r] + bias[ni]);
                    }
                }
        }
        __syncthreads();
#pragma unroll
        for (int i = 0; i < 4; i++) {
            int s = t + i * 512;
            int row = s >> 4, seg = s & 15;
            int gr = m0 + row;
            if (gr < NNODES)
                *(int4*)(C + (size_t)gr * HID + h * 128 + seg * 8) =
                    *(const int4*)(Cs + row * 136 + seg * 8);
        }
        __syncthreads();
    }
}

// -------- Phase 2: out[e] = relu(U[s]+V[d]) . W2 + b2   (b1 folded into U) --------
// 4 edges per wave: all 8 row-gathers issued before the reductions.
__global__ __launch_bounds__(256) void edge_score_bf16(
    const unsigned short* __restrict__ U, const unsigned short* __restrict__ V,
    const float* __restrict__ W2, const float* __restrict__ b2,
    const int* __restrict__ epos, const int* __restrict__ eneg,
    float* __restrict__ out)
{
    const int w = threadIdx.x >> 6, lane = threadIdx.x & 63;
    const int ebase = blockIdx.x * 16 + w * 4;

    const float4 w2 = *(const float4*)(W2 + lane * 4);

    const int* ei = (ebase < NEDGE) ? epos : eneg;
    const int eb2 = (ebase < NEDGE) ? ebase : ebase - NEDGE;

    int sidx[4], didx[4];
#pragma unroll
    for (int j = 0; j < 4; j++) {
        sidx[j] = ei[eb2 + j];
        didx[j] = ei[NEDGE + eb2 + j];
    }
    ushort4 uu[4], vv[4];
#pragma unroll
    for (int j = 0; j < 4; j++) {
        uu[j] = *(const ushort4*)(U + (size_t)sidx[j] * HID + lane * 4);
        vv[j] = *(const ushort4*)(V + (size_t)didx[j] * HID + lane * 4);
    }
    const float bb2 = b2[0];
#pragma unroll
    for (int j = 0; j < 4; j++) {
        float p = fmaxf(bf16_to_f32(uu[j].x) + bf16_to_f32(vv[j].x), 0.f) * w2.x
                + fmaxf(bf16_to_f32(uu[j].y) + bf16_to_f32(vv[j].y), 0.f) * w2.y
                + fmaxf(bf16_to_f32(uu[j].z) + bf16_to_f32(vv[j].z), 0.f) * w2.z
                + fmaxf(bf16_to_f32(uu[j].w) + bf16_to_f32(vv[j].w), 0.f) * w2.w;
#pragma unroll
        for (int off = 32; off; off >>= 1)
            p += __shfl_down(p, off, 64);
        if (lane == 0) out[ebase + j] = p + bb2;
    }
}

// -------- Fallback (ws too small): direct per-edge MLP --------
__global__ __launch_bounds__(256) void edge_score_direct(
    const float* __restrict__ xs_, const float* __restrict__ xd_,
    const float* __restrict__ W1, const float* __restrict__ b1,
    const float* __restrict__ W2, const float* __restrict__ b2,
    const int* __restrict__ epos, const int* __restrict__ eneg,
    float* __restrict__ out)
{
    __shared__ float xrow[2 * D_IN];
    __shared__ float red[256];
    const int e = blockIdx.x;
    const int* ei = (e < NEDGE) ? epos : eneg;
    const int e2  = (e < NEDGE) ? e : e - NEDGE;
    const int s = ei[e2];
    const int d = ei[NEDGE + e2];
    const int t = threadIdx.x;

    xrow[t]        = xs_[(size_t)s * D_IN + t];
    xrow[D_IN + t] = xd_[(size_t)d * D_IN + t];
    __syncthreads();

    float acc = b1[t];
    for (int k = 0; k < 2 * D_IN; k++)
        acc += xrow[k] * W1[(size_t)k * HID + t];
    acc = fmaxf(acc, 0.f);
    red[t] = acc * W2[t];
    __syncthreads();
    for (int st = 128; st; st >>= 1) {
        if (t < st) red[t] += red[t + st];
        __syncthreads();
    }
    if (t == 0) out[e] = red[0] + b2[0];
}

extern "C" void kernel_launch(void* const* d_in, const int* in_sizes, int n_in,
                              void* d_out, int out_size, void* d_ws, size_t ws_size,
                              hipStream_t stream) {
    const float* x_src = (const float*)d_in[0];
    const float* x_dst = (const float*)d_in[1];
    const float* W1    = (const float*)d_in[2];
    const float* b1    = (const float*)d_in[3];
    const float* W2    = (const float*)d_in[4];
    const float* b2    = (const float*)d_in[5];
    const int*   epos  = (const int*)d_in[6];
    const int*   eneg  = (const int*)d_in[7];
    float* out = (float*)d_out;

    const size_t uv   = (size_t)NNODES * HID;                      // 25.6M elems
    const size_t need = (2 * uv + 2 * 256 * 256) * sizeof(unsigned short);
    if (ws_size >= need) {
        unsigned short* U  = (unsigned short*)d_ws;
        unsigned short* V  = U + uv;
        unsigned short* Wt = V + uv;
        convert_w<<<512, 256, 0, stream>>>(W1, Wt);
        dim3 g1((NNODES + 127) / 128, 1, 2);
        gemm_xw_mfma<<<g1, 512, 0, stream>>>(x_src, x_dst, Wt, b1, U, V);
        edge_score_bf16<<<(2 * NEDGE) / 16, 256, 0, stream>>>(U, V, W2, b2, epos, eneg, out);
    } else {
        edge_score_direct<<<2 * NEDGE, 256, 0, stream>>>(x_src, x_dst, W1, b1, W2, b2, epos, eneg, out);
    }
}